// Round 14
// baseline (24.471 us; speedup 1.0000x reference)
//
#include <hip/hip_runtime.h>

// TreeLoss: 2-level hierarchical softmax loss.
// z(b)    = 1 + sum_p e^{x_p} * (1 + sum_{c in p} e^{x_c})   (parents p=56..63)
// loss(b) = log z - (x_g + x_parent(g)),  parent(g) = 56 + g/7; out = mean.
//
// R14 = R11 body (best: 20.08us) + HIERARCHICAL in-kernel finalization,
// replacing the final kernel + inter-node gap. Cost model from R9/R12:
// relaxed same-line atomic RMW ~10ns serialized; release/ACQ_REL ~48ns.
// So: 1024 block partials -> atomicAdd into 64 slots on DISTINCT 128B lines
// (16 adds/line ~ 160ns, lines parallel) -> vmcnt(0) -> relaxed fetch_add on
// per-group counter (16/line) -> 64 group-finishers bump one global counter
// (64 RMWs ~ 0.6us) -> last finisher's wave atomic-loads the 64 slots and
// writes out[0]. Only wave 0 of each block participates (waves 1-3 retire;
// flag via intra-wave __shfl -- no R4-style block-wide wait).
// ws[0..16639] zeroed per call by one async memset (graph-capturable).

#define THREADS 256               // 4 waves
#define WROWS   32                // rows per tile
#define RPB     256               // rows per block (4 waves x 2 tiles x 32)
#define GROUPS  64
// ws layout (128B-strided lines): group_acc f32 @ g*128; group_cnt i32 @
// 8192+g*128; final_cnt i32 @ 16384.

__device__ __forceinline__ float elem(const float4& v, int j) {
    return j == 0 ? v.x : j == 1 ? v.y : j == 2 ? v.z : v.w;
}

__device__ __forceinline__ void stage_tile(const float* __restrict__ pred,
                                           int rowBase, float* ldsReg,
                                           int l, int rows) {
    #pragma unroll
    for (int i = 0; i < 8; ++i) {
        const int f   = i * 64 + l;          // LDS chunk slot 0..511
        const int rr  = f >> 4;              // tile row 0..31
        const int sc  = (f & 15) ^ (rr & 7); // pre-swizzled source chunk
        const int row = rowBase + rr;
        if (row < rows) {
            const float* src = pred + (size_t)row * 64 + sc * 4;
            __builtin_amdgcn_global_load_lds(
                (const __attribute__((address_space(1))) float*)src,
                (__attribute__((address_space(3))) float*)(ldsReg + i * 256),
                16, 0, 0);                   // lane l lands at +l*16B = slot f
        }
    }
}

// One row handled by 2 lanes (r = l&31 row, hi = l>>5 parent-half).
__device__ __forceinline__ float compute_half(const float* ldsReg, int g,
                                              int r, int hi) {
    const int x7 = r & 7;
    const float* rowp = ldsReg + r * 64;

    float4 ch[7];
    #pragma unroll
    for (int k = 0; k < 7; ++k) {
        const int c = (7 * hi + k) ^ x7;               // swizzled read
        ch[k] = *(const float4*)(rowp + c * 4);        // ds_read_b128
    }
    const float4 pv = *(const float4*)(rowp + ((14 + hi) ^ x7) * 4);

    float zh = 0.f;
    #pragma unroll
    for (int p = 0; p < 4; ++p) {
        float s = 1.f;
        #pragma unroll
        for (int c = 0; c < 7; ++c) {
            const int idx = p * 7 + c;                 // compile-time
            s += __expf(elem(ch[idx >> 2], idx & 3));
        }
        zh += __expf(elem(pv, p)) * s;
    }
    const float zo = __shfl_xor(zh, 32);               // other parent-half

    const int cg = (g >> 2) ^ x7;
    const float xg = rowp[cg * 4 + (g & 3)];
    const int wp = 56 + g / 7;
    const int cpg = (wp >> 2) ^ x7;
    const float xp = rowp[cpg * 4 + (wp & 3)];

    return __logf(1.f + zh + zo) - xg - xp;
}

__global__ void __launch_bounds__(THREADS) tree_loss(
    const float* __restrict__ pred,   // [rows, 64]
    const int*   __restrict__ gt,     // [rows] 0..55
    char*        __restrict__ ws,     // zeroed [0,16640) each call
    float*       __restrict__ out,
    int rows, float inv)
{
    __shared__ float lds[4 * 2 * WROWS * 64];   // 65536 B -> 2 blocks/CU
    __shared__ float wsum[4];

    const int t  = threadIdx.x;
    const int w  = t >> 6;
    const int l  = t & 63;
    const int r  = l & 31;
    const int hi = l >> 5;

    float* regA = &lds[(w * 2 + 0) * WROWS * 64];
    float* regB = &lds[(w * 2 + 1) * WROWS * 64];

    const int rbA = (int)blockIdx.x * RPB + w * 64;
    const int rbB = rbA + WROWS;
    const int rowA = rbA + r, rowB = rbB + r;

    // gt loads FIRST (oldest in vmcnt queue -> retired by the vmcnt(8) wait).
    const int gA = gt[min(rowA, rows - 1)];
    const int gB = gt[min(rowB, rows - 1)];

    stage_tile(pred, rbA, regA, l, rows);   // 8 DMAs
    stage_tile(pred, rbB, regB, l, rows);   // 8 DMAs (queue: 2 gt + 16)

    asm volatile("s_waitcnt vmcnt(8)" ::: "memory");   // gt + tile A complete
    const float lossA = compute_half(regA, gA, r, hi);

    asm volatile("s_waitcnt vmcnt(0)" ::: "memory");   // tile B complete
    const float lossB = compute_half(regB, gB, r, hi);

    float acc = 0.f;
    if (hi == 0 && rowA < rows) acc += lossA;
    if (hi == 0 && rowB < rows) acc += lossB;

    #pragma unroll
    for (int off = 32; off; off >>= 1) acc += __shfl_xor(acc, off);
    if (l == 0) wsum[w] = acc;
    __syncthreads();
    if (w != 0) return;                      // waves 1-3 retire immediately

    // ---- Hierarchical finalization (wave 0 only) ----
    int flag = 0;
    if (l == 0) {
        const float blockAcc = wsum[0] + wsum[1] + wsum[2] + wsum[3];
        const int g = (int)blockIdx.x & (GROUPS - 1);
        float* gacc = (float*)(ws + (size_t)g * 128);
        int*   gcnt = (int*)(ws + 8192 + (size_t)g * 128);
        int*   fcnt = (int*)(ws + 16384);

        atomicAdd(gacc, blockAcc);                        // relaxed, 16/line
        asm volatile("s_waitcnt vmcnt(0)" ::: "memory");  // slot add complete
        const int expected = ((int)gridDim.x - g + (GROUPS - 1)) >> 6;
        const int old = __hip_atomic_fetch_add(gcnt, 1, __ATOMIC_RELAXED,
                                               __HIP_MEMORY_SCOPE_AGENT);
        if (old == expected - 1) {                        // group finisher
            const int nact = min((int)gridDim.x, GROUPS);
            const int old2 = __hip_atomic_fetch_add(fcnt, 1, __ATOMIC_RELAXED,
                                                    __HIP_MEMORY_SCOPE_AGENT);
            flag = (old2 == nact - 1);                    // global finisher
        }
    }
    flag = __shfl(flag, 0);                  // intra-wave, no barrier
    if (flag) {
        // All 1024 slot-adds complete (counter chain). Lane k reads slot k.
        float s = 0.f;
        if (l < GROUPS)
            s = __hip_atomic_load((const float*)(ws + (size_t)l * 128),
                                  __ATOMIC_RELAXED, __HIP_MEMORY_SCOPE_AGENT);
        #pragma unroll
        for (int off = 32; off; off >>= 1) s += __shfl_xor(s, off);
        if (l == 0) out[0] = s * inv;
    }
}

extern "C" void kernel_launch(void* const* d_in, const int* in_sizes, int n_in,
                              void* d_out, int out_size, void* d_ws, size_t ws_size,
                              hipStream_t stream) {
    const float* pred = (const float*)d_in[0];   // [B,64] fp32
    const int*   gt   = (const int*)d_in[1];     // [B] int32
    float* out = (float*)d_out;
    const int rows = in_sizes[1];                // BATCH = 262144

    hipMemsetAsync(d_ws, 0, 16640, stream);      // slots + counters
    const int blocks = (rows + RPB - 1) / RPB;   // 1024
    tree_loss<<<blocks, THREADS, 0, stream>>>(pred, gt, (char*)d_ws, out,
                                              rows, 1.0f / (float)rows);
}

// Round 15
// 19.763 us; speedup vs baseline: 1.2383x; 1.2383x over previous
//
#include <hip/hip_runtime.h>

// TreeLoss: 2-level hierarchical softmax loss.
// z(b)    = 1 + sum_p e^{x_p} * (1 + sum_{c in p} e^{x_c})   (parents p=56..63)
// loss(b) = log z - (x_g + x_parent(g)),  parent(g) = 56 + g/7; out = mean.
//
// R15 = R11 (session best, 20.08us) restored + float4 final-kernel loads.
// Session conclusions baked in:
//  - partial body is read-ceiling-bound (~4.2 TB/s): 7 body variants within
//    12%; staging mechanism/occupancy/barriers/pipeline-depth all neutral.
//  - two-dispatch reduction is mandatory: all in-kernel finalizations
//    (flat atomicAdd, ACQ_REL handshake, hierarchical 64-line) cost +4..47us
//    in serialized coherence-point RMWs.
// Body: global_load_lds HBM->LDS (no VGPR round trip), source-chunk XOR
// swizzle + same involution on LDS reads (bank-uniform), 2 tiles/wave with
// counted vmcnt (tile-B latency hidden under compute-A), no __syncthreads,
// per-wave partials.

#define THREADS 256               // 4 waves
#define WROWS   32                // rows per tile
#define RPB     256               // rows per block (4 waves x 2 tiles x 32)

__device__ __forceinline__ float elem(const float4& v, int j) {
    return j == 0 ? v.x : j == 1 ? v.y : j == 2 ? v.z : v.w;
}

__device__ __forceinline__ void stage_tile(const float* __restrict__ pred,
                                           int rowBase, float* ldsReg,
                                           int l, int rows) {
    #pragma unroll
    for (int i = 0; i < 8; ++i) {
        const int f   = i * 64 + l;          // LDS chunk slot 0..511
        const int rr  = f >> 4;              // tile row 0..31
        const int sc  = (f & 15) ^ (rr & 7); // pre-swizzled source chunk
        const int row = rowBase + rr;
        if (row < rows) {
            const float* src = pred + (size_t)row * 64 + sc * 4;
            __builtin_amdgcn_global_load_lds(
                (const __attribute__((address_space(1))) float*)src,
                (__attribute__((address_space(3))) float*)(ldsReg + i * 256),
                16, 0, 0);                   // lane l lands at +l*16B = slot f
        }
    }
}

// One row handled by 2 lanes (r = l&31 row, hi = l>>5 parent-half).
__device__ __forceinline__ float compute_half(const float* ldsReg, int g,
                                              int r, int hi) {
    const int x7 = r & 7;
    const float* rowp = ldsReg + r * 64;

    float4 ch[7];
    #pragma unroll
    for (int k = 0; k < 7; ++k) {
        const int c = (7 * hi + k) ^ x7;               // swizzled read
        ch[k] = *(const float4*)(rowp + c * 4);        // ds_read_b128
    }
    const float4 pv = *(const float4*)(rowp + ((14 + hi) ^ x7) * 4);

    float zh = 0.f;
    #pragma unroll
    for (int p = 0; p < 4; ++p) {
        float s = 1.f;
        #pragma unroll
        for (int c = 0; c < 7; ++c) {
            const int idx = p * 7 + c;                 // compile-time
            s += __expf(elem(ch[idx >> 2], idx & 3));
        }
        zh += __expf(elem(pv, p)) * s;
    }
    const float zo = __shfl_xor(zh, 32);               // other parent-half

    const int cg = (g >> 2) ^ x7;
    const float xg = rowp[cg * 4 + (g & 3)];
    const int wp = 56 + g / 7;
    const int cpg = (wp >> 2) ^ x7;
    const float xp = rowp[cpg * 4 + (wp & 3)];

    return __logf(1.f + zh + zo) - xg - xp;
}

__global__ void __launch_bounds__(THREADS) tree_loss_partial(
    const float* __restrict__ pred,   // [rows, 64]
    const int*   __restrict__ gt,     // [rows] 0..55
    float*       __restrict__ partial,// [gridDim.x * 4]
    int rows)
{
    __shared__ float lds[4 * 2 * WROWS * 64];   // 65536 B -> 2 blocks/CU

    const int t  = threadIdx.x;
    const int w  = t >> 6;
    const int l  = t & 63;
    const int r  = l & 31;
    const int hi = l >> 5;

    float* regA = &lds[(w * 2 + 0) * WROWS * 64];
    float* regB = &lds[(w * 2 + 1) * WROWS * 64];

    const int rbA = (int)blockIdx.x * RPB + w * 64;  // wave rows: A, then B
    const int rbB = rbA + WROWS;
    const int rowA = rbA + r, rowB = rbB + r;

    // gt loads FIRST (oldest vmem -> covered by the vmcnt(8) wait).
    const int gA = gt[min(rowA, rows - 1)];
    const int gB = gt[min(rowB, rows - 1)];

    // Issue all 16 DMAs back-to-back: 16KB/wave in flight.
    stage_tile(pred, rbA, regA, l, rows);
    stage_tile(pred, rbB, regB, l, rows);

    asm volatile("s_waitcnt vmcnt(8)" ::: "memory");   // gt + tile A done
    const float lossA = compute_half(regA, gA, r, hi);

    asm volatile("s_waitcnt vmcnt(0)" ::: "memory");   // tile B done
    const float lossB = compute_half(regB, gB, r, hi);

    float acc = 0.f;
    if (hi == 0 && rowA < rows) acc += lossA;
    if (hi == 0 && rowB < rows) acc += lossB;

    #pragma unroll
    for (int off = 32; off; off >>= 1) acc += __shfl_xor(acc, off);
    if (l == 0) partial[(size_t)blockIdx.x * 4 + w] = acc;  // per-wave, no barrier
}

__global__ void __launch_bounds__(1024) tree_loss_final(
    const float* __restrict__ partial, int n4,  // n4 = count of float4s
    float* __restrict__ out, float inv)
{
    float s = 0.0f;
    const float4* p4 = (const float4*)partial;
    for (int i = threadIdx.x; i < n4; i += 1024) {
        float4 v = p4[i];
        s += (v.x + v.y) + (v.z + v.w);
    }
    #pragma unroll
    for (int off = 32; off; off >>= 1) s += __shfl_xor(s, off);
    __shared__ float w[16];
    const int lane = threadIdx.x & 63;
    const int wv   = threadIdx.x >> 6;
    if (lane == 0) w[wv] = s;
    __syncthreads();
    if (threadIdx.x == 0) {
        float b = 0.f;
        #pragma unroll
        for (int k = 0; k < 16; ++k) b += w[k];
        out[0] = b * inv;
    }
}

extern "C" void kernel_launch(void* const* d_in, const int* in_sizes, int n_in,
                              void* d_out, int out_size, void* d_ws, size_t ws_size,
                              hipStream_t stream) {
    const float* pred = (const float*)d_in[0];   // [B,64] fp32
    const int*   gt   = (const int*)d_in[1];     // [B] int32
    float* out     = (float*)d_out;
    float* partial = (float*)d_ws;
    const int rows = in_sizes[1];                // BATCH = 262144

    const int blocks = (rows + RPB - 1) / RPB;   // 1024
    tree_loss_partial<<<blocks, THREADS, 0, stream>>>(pred, gt, partial, rows);
    tree_loss_final<<<1, 1024, 0, stream>>>(partial, blocks, out,  // blocks = 4096/4 float4s
                                            1.0f / (float)rows);
}